// Round 5
// baseline (264.585 us; speedup 1.0000x reference)
//
#include <hip/hip_runtime.h>
#include <hip/hip_bf16.h>
#include <math.h>

#define Bq 64
#define Tq 2048
#define Eq 256
#define Dq 256
#define Iq 256

using short8  = __attribute__((ext_vector_type(8))) short;
using floatx4 = __attribute__((ext_vector_type(4))) float;

__device__ __forceinline__ float fast_tanh(float x) {
    float e = __expf(2.0f * x);
    return 1.0f - 2.0f / (e + 1.0f);
}

__device__ __forceinline__ ushort f2bf(float x) {
    union { __hip_bfloat16 h; ushort u; } c;
    c.h = __float2bfloat16(x);
    return c.u;
}

// Fused prep:
//  blocks 0..31 : w1 fp32 -> bf16 fragment-ordered: w1sw[kc][i][8], kc=k/8
//  blocks 32..95: dec_proj[b][i] = sum_d dec[b][d]*w2[i][d], b=blockIdx-32
__global__ __launch_bounds__(256) void prep_kernel(
    const float* __restrict__ w1, ushort* __restrict__ w1sw,
    const float* __restrict__ dec, const float* __restrict__ w2,
    float* __restrict__ dproj)
{
    if (blockIdx.x < 32) {
        const int kc = blockIdx.x;
        const int i  = threadIdx.x;
        const float* src = w1 + i * Eq + kc * 8;
        float4 f0 = *(const float4*)src;
        float4 f1 = *(const float4*)(src + 4);
        ushort u[8] = { f2bf(f0.x), f2bf(f0.y), f2bf(f0.z), f2bf(f0.w),
                        f2bf(f1.x), f2bf(f1.y), f2bf(f1.z), f2bf(f1.w) };
        *(short8*)&w1sw[(kc * 256 + i) * 8] = *(short8*)u;
    } else {
        const int b = blockIdx.x - 32;
        const int i = threadIdx.x;
        __shared__ float dls[Dq];
        dls[i] = dec[b * Dq + i];
        __syncthreads();
        const float* w2r = w2 + i * Dq;
        float acc = 0.f;
        #pragma unroll 8
        for (int d = 0; d < Dq; ++d) acc += dls[d] * w2r[d];
        dproj[b * Iq + i] = acc;
    }
}

// Fused scores + unnormalized-context. BARRIER-FREE main loop:
// A and B fragments are loaded straight from global into VGPRs
// (B is L2-resident fragment-ordered w1sw; A is enc with per-quad 128B lines),
// fp32->bf16 cvt in registers, MFMA from registers. No LDS until epilogue.
__global__ __launch_bounds__(256, 3) void scores_ctx_kernel(
    const float*  __restrict__ enc,    // [B][T][E] fp32
    const ushort* __restrict__ w1sw,   // fragment-ordered bf16 [32 kc][256 i][8]
    const float*  __restrict__ v,      // [I]
    const float*  __restrict__ dproj,  // [B][I]
    float* __restrict__ escore,        // [B][T] unnormalized exp (probs buffer)
    float* __restrict__ ctxp,          // [32][B][E] context partials
    float* __restrict__ denomp)        // [32][B]
{
    const int b   = blockIdx.y;
    const int bx  = blockIdx.x;
    const int t0  = bx * 64;
    const int tid = threadIdx.x;
    const int w   = tid >> 6;
    const int l   = tid & 63;
    const int l15 = l & 15;
    const int lq  = l >> 4;
    const int iBase = w * 64 + l15;

    __shared__ float red2[256 * 20];   // 20.5 KB transpose-reduce / context redux
    __shared__ float vls[Iq], dls[Iq];
    __shared__ float pv[64];

    vls[tid] = v[tid];
    dls[tid] = dproj[b * Iq + tid];

    floatx4 acc[4][4];
    #pragma unroll
    for (int mi = 0; mi < 4; ++mi)
        #pragma unroll
        for (int ni = 0; ni < 4; ++ni)
            acc[mi][ni] = (floatx4)0.f;

    const float* encB   = enc + ((size_t)b * Tq + t0) * Eq;
    const float* encRow = encB + l15 * Eq;     // row for mi=0

    #pragma unroll
    for (int k0 = 0; k0 < Eq; k0 += 64) {
        #pragma unroll
        for (int ks = 0; ks < 2; ++ks) {
            const int kf = k0 + ks * 32 + lq * 8;   // this lane's k-octet (floats)
            const int kc = kf >> 3;                 // k-chunk index in w1sw
            // B fragments: 16 lanes x 16 B contiguous per (ni,lq) -> coalesced
            short8 bfv[4];
            #pragma unroll
            for (int ni = 0; ni < 4; ++ni)
                bfv[ni] = *(const short8*)&w1sw[((size_t)kc * 256 + iBase + ni * 16) * 8];
            // A fragments: per (mi): quad reads one 128-B line; cvt in VGPRs
            #pragma unroll
            for (int mi = 0; mi < 4; ++mi) {
                const float* ap = encRow + mi * 16 * Eq + kf;
                float4 f0 = *(const float4*)(ap);
                float4 f1 = *(const float4*)(ap + 4);
                ushort u[8] = { f2bf(f0.x), f2bf(f0.y), f2bf(f0.z), f2bf(f0.w),
                                f2bf(f1.x), f2bf(f1.y), f2bf(f1.z), f2bf(f1.w) };
                short8 af = *(short8*)u;
                #pragma unroll
                for (int ni = 0; ni < 4; ++ni)
                    acc[mi][ni] = __builtin_amdgcn_mfma_f32_16x16x32_bf16(
                        af, bfv[ni], acc[mi][ni], 0, 0, 0);
            }
        }
    }

    // epilogue: tanh + v-weight. C layout: col(i)=l15, row(t)=lq*4+reg.
    float part[4][4];
    #pragma unroll
    for (int mi = 0; mi < 4; ++mi)
        #pragma unroll
        for (int r = 0; r < 4; ++r) part[mi][r] = 0.f;

    #pragma unroll
    for (int ni = 0; ni < 4; ++ni) {
        const int i   = w * 64 + ni * 16 + l15;
        const float vi = vls[i];
        const float dp = dls[i];
        #pragma unroll
        for (int mi = 0; mi < 4; ++mi)
            #pragma unroll
            for (int r = 0; r < 4; ++r)
                part[mi][r] += vi * fast_tanh(acc[mi][ni][r] + dp);
    }

    // LDS transpose-reduce: red2[(w*64 + t_local)*20 + l15]
    #pragma unroll
    for (int mi = 0; mi < 4; ++mi)
        #pragma unroll
        for (int r = 0; r < 4; ++r)
            red2[(w * 64 + mi * 16 + lq * 4 + r) * 20 + l15] = part[mi][r];
    __syncthreads();

    if (tid < 64) {
        float s = 0.f;
        #pragma unroll
        for (int ww = 0; ww < 4; ++ww) {
            const float* rp = red2 + (ww * 64 + tid) * 20;
            float4 q0 = *(const float4*)(rp + 0);
            float4 q1 = *(const float4*)(rp + 4);
            float4 q2 = *(const float4*)(rp + 8);
            float4 q3 = *(const float4*)(rp + 12);
            s += (q0.x + q0.y + q0.z + q0.w) + (q1.x + q1.y + q1.z + q1.w)
               + (q2.x + q2.y + q2.z + q2.w) + (q3.x + q3.y + q3.z + q3.w);
        }
        const float es = __expf(s);   // |s| <= 16 -> safe in fp32 w/o max-sub
        pv[tid] = es;
        escore[(size_t)b * Tq + t0 + tid] = es;
        float tot = es;
        tot += __shfl_xor(tot, 1);  tot += __shfl_xor(tot, 2);
        tot += __shfl_xor(tot, 4);  tot += __shfl_xor(tot, 8);
        tot += __shfl_xor(tot, 16); tot += __shfl_xor(tot, 32);
        if (tid == 0) denomp[bx * Bq + b] = tot;
    }
    __syncthreads();

    // fused context partial: ctxp[bx][b][e] = sum_t pv[t]*enc[t][e] (L2-hot tile)
    const int tg = tid >> 6;            // t quarter 0..3
    const int el = (tid & 63) * 4;      // e in float4 units
    float4 a = {0.f, 0.f, 0.f, 0.f};
    #pragma unroll 4
    for (int tt = 0; tt < 16; ++tt) {
        const int t = tg * 16 + tt;     // wave-uniform
        const float pt = pv[t];
        float4 ev = *(const float4*)&encB[t * Eq + el];
        a.x += pt * ev.x; a.y += pt * ev.y; a.z += pt * ev.z; a.w += pt * ev.w;
    }
    float* redf = red2;                 // reuse (safe: barrier above passed)
    *(float4*)&redf[tg * 256 + el] = a;
    __syncthreads();
    if (tg == 0) {
        float4 a0 = *(const float4*)&redf[0 * 256 + el];
        float4 a1 = *(const float4*)&redf[1 * 256 + el];
        float4 a2 = *(const float4*)&redf[2 * 256 + el];
        float4 a3 = *(const float4*)&redf[3 * 256 + el];
        float4 o;
        o.x = a0.x + a1.x + a2.x + a3.x;
        o.y = a0.y + a1.y + a2.y + a3.y;
        o.z = a0.z + a1.z + a2.z + a3.z;
        o.w = a0.w + a1.w + a2.w + a3.w;
        *(float4*)&ctxp[((size_t)bx * Bq + b) * Eq + el] = o;
    }
}

// One block per b: denom = sum_c denomp[c][b]; probs *= 1/denom (in place);
// ctx[b][e] = (sum_c ctxp[c][b][e]) / denom.
__global__ __launch_bounds__(256) void finalize_kernel(
    const float* __restrict__ ctxp, const float* __restrict__ denomp,
    float* __restrict__ probs, float* __restrict__ ctx)
{
    const int b   = blockIdx.x;
    const int tid = threadIdx.x;

    float d = denomp[(tid & 31) * Bq + b];
    d += __shfl_xor(d, 1);  d += __shfl_xor(d, 2);  d += __shfl_xor(d, 4);
    d += __shfl_xor(d, 8);  d += __shfl_xor(d, 16);
    const float inv = 1.0f / d;

    float* prow = probs + (size_t)b * Tq + tid * 8;
    float4 p0 = *(const float4*)(prow + 0);
    float4 p1 = *(const float4*)(prow + 4);
    p0.x *= inv; p0.y *= inv; p0.z *= inv; p0.w *= inv;
    p1.x *= inv; p1.y *= inv; p1.z *= inv; p1.w *= inv;
    *(float4*)(prow + 0) = p0;
    *(float4*)(prow + 4) = p1;

    float s = 0.f;
    #pragma unroll 8
    for (int c = 0; c < 32; ++c)
        s += ctxp[((size_t)c * Bq + b) * Eq + tid];
    ctx[b * Eq + tid] = s * inv;
}

extern "C" void kernel_launch(void* const* d_in, const int* in_sizes, int n_in,
                              void* d_out, int out_size, void* d_ws, size_t ws_size,
                              hipStream_t stream) {
    const float* enc = (const float*)d_in[0];  // [64][2048][256]
    const float* dec = (const float*)d_in[1];  // [64][256]
    const float* w1  = (const float*)d_in[2];  // [256][256]
    const float* w2  = (const float*)d_in[3];  // [256][256]
    const float* v   = (const float*)d_in[4];  // [1][256]

    float* out   = (float*)d_out;
    float* ctx   = out;                 // [64][256]  output 0
    float* probs = out + Bq * Eq;       // [64][2048] output 1 (escore first)

    char* ws = (char*)d_ws;
    float*  ctxp   = (float*)ws;                        // 2 MB  [32][64][256]
    float*  denomp = (float*)(ws + (32*Bq*Eq)*4);       // 8 KB  [32][64]
    float*  dproj  = (float*)(ws + (32*Bq*Eq)*4 + 32*Bq*4);            // 64 KB
    ushort* w1sw   = (ushort*)(ws + (32*Bq*Eq)*4 + 32*Bq*4 + Bq*Iq*4); // 128 KB

    // all ws buffers are fully overwritten each call -> no memsets needed
    prep_kernel<<<dim3(96), dim3(256), 0, stream>>>(w1, w1sw, dec, w2, dproj);
    scores_ctx_kernel<<<dim3(Tq / 64, Bq), dim3(256), 0, stream>>>(
        enc, w1sw, v, dproj, probs, ctxp, denomp);
    finalize_kernel<<<dim3(Bq), dim3(256), 0, stream>>>(ctxp, denomp, probs, ctx);
}

// Round 6
// 234.489 us; speedup vs baseline: 1.1283x; 1.1283x over previous
//
#include <hip/hip_runtime.h>
#include <hip/hip_bf16.h>
#include <math.h>

#define Bq 64
#define Tq 2048
#define Eq 256
#define Dq 256
#define Iq 256

using short8  = __attribute__((ext_vector_type(8))) short;
using floatx4 = __attribute__((ext_vector_type(4))) float;

__device__ __forceinline__ float fast_tanh(float x) {
    float e = __expf(2.0f * x);
    return 1.0f - 2.0f / (e + 1.0f);
}

__device__ __forceinline__ ushort f2bf(float x) {
    union { __hip_bfloat16 h; ushort u; } c;
    c.h = __float2bfloat16(x);
    return c.u;
}

// Fused prep:
//  blocks 0..31 : w1 fp32 -> bf16 fragment-ordered: w1sw[kc][i][8], kc=k/8
//  blocks 32..95: dec_proj[b][i] = sum_d dec[b][d]*w2[i][d], b=blockIdx-32
__global__ __launch_bounds__(256) void prep_kernel(
    const float* __restrict__ w1, ushort* __restrict__ w1sw,
    const float* __restrict__ dec, const float* __restrict__ w2,
    float* __restrict__ dproj)
{
    if (blockIdx.x < 32) {
        const int kc = blockIdx.x;
        const int i  = threadIdx.x;
        const float* src = w1 + i * Eq + kc * 8;
        float4 f0 = *(const float4*)src;
        float4 f1 = *(const float4*)(src + 4);
        ushort u[8] = { f2bf(f0.x), f2bf(f0.y), f2bf(f0.z), f2bf(f0.w),
                        f2bf(f1.x), f2bf(f1.y), f2bf(f1.z), f2bf(f1.w) };
        *(short8*)&w1sw[(kc * 256 + i) * 8] = *(short8*)u;
    } else {
        const int b = blockIdx.x - 32;
        const int i = threadIdx.x;
        __shared__ float dls[Dq];
        dls[i] = dec[b * Dq + i];
        __syncthreads();
        const float* w2r = w2 + i * Dq;
        float acc = 0.f;
        #pragma unroll 8
        for (int d = 0; d < Dq; ++d) acc += dls[d] * w2r[d];
        dproj[b * Iq + i] = acc;
    }
}

// Fused scores + unnormalized-context.
// A (enc tile) staged through double-buffered LDS (coalesced loads, one
// barrier per K-iter, no vmcnt(0) drain). B (w1sw) loaded straight from
// L2 into VGPRs (fragment-ordered -> 8 lines/instr). Context fused.
__global__ __launch_bounds__(256, 3) void scores_ctx_kernel(
    const float*  __restrict__ enc,    // [B][T][E] fp32
    const ushort* __restrict__ w1sw,   // fragment-ordered bf16 [32 kc][256 i][8]
    const float*  __restrict__ v,      // [I]
    const float*  __restrict__ dproj,  // [B][I]
    float* __restrict__ escore,        // [B][T] unnormalized exp (probs buffer)
    float* __restrict__ ctxp,          // [32][B][E] context partials
    float* __restrict__ denomp)        // [32][B]
{
    const int b   = blockIdx.y;
    const int bx  = blockIdx.x;
    const int t0  = bx * 64;
    const int tid = threadIdx.x;
    const int w   = tid >> 6;
    const int l   = tid & 63;
    const int l15 = l & 15;
    const int lq  = l >> 4;
    const int iBase = w * 64 + l15;

    // red2 (epilogue transpose-reduce, 20.5 KB) aliases the two A buffers
    __shared__ float red2[256 * 20];
    ushort* As = (ushort*)red2;              // 2 x 64 x 72 ushorts = 18.4 KB
    __shared__ float vls[Iq], dls[Iq];
    __shared__ float pv[64];

    vls[tid] = v[tid];
    dls[tid] = dproj[b * Iq + tid];

    floatx4 acc[4][4];
    #pragma unroll
    for (int mi = 0; mi < 4; ++mi)
        #pragma unroll
        for (int ni = 0; ni < 4; ++ni)
            acc[mi][ni] = (floatx4)0.f;

    const float* encB = enc + ((size_t)b * Tq + t0) * Eq;
    const int rowp = tid >> 4;          // staging row 0..63 (16 lanes/row)
    const int c4   = (tid & 15) * 4;    // staging col (floats)

    // prefetch k0 = 0
    float4 pre[4];
    #pragma unroll
    for (int r = 0; r < 4; ++r)
        pre[r] = *(const float4*)&encB[(rowp + 16 * r) * Eq + c4];

    #pragma unroll
    for (int kb = 0; kb < 4; ++kb) {          // k0 = kb*64
        ushort* Asp = As + (kb & 1) * (64 * 72);
        // cvt + LDS write of the prefetched tile
        #pragma unroll
        for (int r = 0; r < 4; ++r) {
            ushort4 u;
            u.x = f2bf(pre[r].x); u.y = f2bf(pre[r].y);
            u.z = f2bf(pre[r].z); u.w = f2bf(pre[r].w);
            *(ushort4*)&Asp[(rowp + 16 * r) * 72 + c4] = u;
        }
        __syncthreads();
        // prefetch next k-tile (overlaps MFMA below)
        if (kb < 3) {
            #pragma unroll
            for (int r = 0; r < 4; ++r)
                pre[r] = *(const float4*)&encB[(rowp + 16 * r) * Eq + (kb + 1) * 64 + c4];
        }
        #pragma unroll
        for (int ks = 0; ks < 2; ++ks) {
            const int kc = kb * 8 + ks * 4 + lq;    // k-chunk in w1sw
            short8 bfv[4], af[4];
            #pragma unroll
            for (int ni = 0; ni < 4; ++ni)
                bfv[ni] = *(const short8*)&w1sw[((size_t)kc * 256 + iBase + ni * 16) * 8];
            #pragma unroll
            for (int mi = 0; mi < 4; ++mi)
                af[mi] = *(const short8*)&Asp[(mi * 16 + l15) * 72 + ks * 32 + lq * 8];
            #pragma unroll
            for (int mi = 0; mi < 4; ++mi)
                #pragma unroll
                for (int ni = 0; ni < 4; ++ni)
                    acc[mi][ni] = __builtin_amdgcn_mfma_f32_16x16x32_bf16(
                        af[mi], bfv[ni], acc[mi][ni], 0, 0, 0);
        }
    }

    // epilogue: tanh + v-weight. C layout: col(i)=l15, row(t)=lq*4+reg.
    float part[4][4];
    #pragma unroll
    for (int mi = 0; mi < 4; ++mi)
        #pragma unroll
        for (int r = 0; r < 4; ++r) part[mi][r] = 0.f;

    #pragma unroll
    for (int ni = 0; ni < 4; ++ni) {
        const int i   = w * 64 + ni * 16 + l15;
        const float vi = vls[i];
        const float dp = dls[i];
        #pragma unroll
        for (int mi = 0; mi < 4; ++mi)
            #pragma unroll
            for (int r = 0; r < 4; ++r)
                part[mi][r] += vi * fast_tanh(acc[mi][ni][r] + dp);
    }

    __syncthreads();   // all waves done reading As before red2 overwrite

    // LDS transpose-reduce: red2[(w*64 + t_local)*20 + l15]
    #pragma unroll
    for (int mi = 0; mi < 4; ++mi)
        #pragma unroll
        for (int r = 0; r < 4; ++r)
            red2[(w * 64 + mi * 16 + lq * 4 + r) * 20 + l15] = part[mi][r];
    __syncthreads();

    if (tid < 64) {
        float s = 0.f;
        #pragma unroll
        for (int ww = 0; ww < 4; ++ww) {
            const float* rp = red2 + (ww * 64 + tid) * 20;
            float4 q0 = *(const float4*)(rp + 0);
            float4 q1 = *(const float4*)(rp + 4);
            float4 q2 = *(const float4*)(rp + 8);
            float4 q3 = *(const float4*)(rp + 12);
            s += (q0.x + q0.y + q0.z + q0.w) + (q1.x + q1.y + q1.z + q1.w)
               + (q2.x + q2.y + q2.z + q2.w) + (q3.x + q3.y + q3.z + q3.w);
        }
        const float es = __expf(s);   // |s| <= 16 -> safe in fp32 w/o max-sub
        pv[tid] = es;
        escore[(size_t)b * Tq + t0 + tid] = es;
        float tot = es;
        tot += __shfl_xor(tot, 1);  tot += __shfl_xor(tot, 2);
        tot += __shfl_xor(tot, 4);  tot += __shfl_xor(tot, 8);
        tot += __shfl_xor(tot, 16); tot += __shfl_xor(tot, 32);
        if (tid == 0) denomp[bx * Bq + b] = tot;
    }
    __syncthreads();

    // fused context partial: ctxp[bx][b][e] = sum_t pv[t]*enc[t][e] (L2-hot tile)
    const int tg = tid >> 6;            // t quarter 0..3
    const int el = (tid & 63) * 4;      // e in float4 units
    float4 a = {0.f, 0.f, 0.f, 0.f};
    #pragma unroll 4
    for (int tt = 0; tt < 16; ++tt) {
        const int t = tg * 16 + tt;     // wave-uniform
        const float pt = pv[t];
        float4 ev = *(const float4*)&encB[t * Eq + el];
        a.x += pt * ev.x; a.y += pt * ev.y; a.z += pt * ev.z; a.w += pt * ev.w;
    }
    float* redf = red2;                 // reuse (barrier above passed)
    *(float4*)&redf[tg * 256 + el] = a;
    __syncthreads();
    if (tg == 0) {
        float4 a0 = *(const float4*)&redf[0 * 256 + el];
        float4 a1 = *(const float4*)&redf[1 * 256 + el];
        float4 a2 = *(const float4*)&redf[2 * 256 + el];
        float4 a3 = *(const float4*)&redf[3 * 256 + el];
        float4 o;
        o.x = a0.x + a1.x + a2.x + a3.x;
        o.y = a0.y + a1.y + a2.y + a3.y;
        o.z = a0.z + a1.z + a2.z + a3.z;
        o.w = a0.w + a1.w + a2.w + a3.w;
        *(float4*)&ctxp[((size_t)bx * Bq + b) * Eq + el] = o;
    }
}

// One block per b: denom = sum_c denomp[c][b]; probs *= 1/denom (in place);
// ctx[b][e] = (sum_c ctxp[c][b][e]) / denom.
__global__ __launch_bounds__(256) void finalize_kernel(
    const float* __restrict__ ctxp, const float* __restrict__ denomp,
    float* __restrict__ probs, float* __restrict__ ctx)
{
    const int b   = blockIdx.x;
    const int tid = threadIdx.x;

    float d = denomp[(tid & 31) * Bq + b];
    d += __shfl_xor(d, 1);  d += __shfl_xor(d, 2);  d += __shfl_xor(d, 4);
    d += __shfl_xor(d, 8);  d += __shfl_xor(d, 16);
    const float inv = 1.0f / d;

    float* prow = probs + (size_t)b * Tq + tid * 8;
    float4 p0 = *(const float4*)(prow + 0);
    float4 p1 = *(const float4*)(prow + 4);
    p0.x *= inv; p0.y *= inv; p0.z *= inv; p0.w *= inv;
    p1.x *= inv; p1.y *= inv; p1.z *= inv; p1.w *= inv;
    *(float4*)(prow + 0) = p0;
    *(float4*)(prow + 4) = p1;

    float s = 0.f;
    #pragma unroll 8
    for (int c = 0; c < 32; ++c)
        s += ctxp[((size_t)c * Bq + b) * Eq + tid];
    ctx[b * Eq + tid] = s * inv;
}

extern "C" void kernel_launch(void* const* d_in, const int* in_sizes, int n_in,
                              void* d_out, int out_size, void* d_ws, size_t ws_size,
                              hipStream_t stream) {
    const float* enc = (const float*)d_in[0];  // [64][2048][256]
    const float* dec = (const float*)d_in[1];  // [64][256]
    const float* w1  = (const float*)d_in[2];  // [256][256]
    const float* w2  = (const float*)d_in[3];  // [256][256]
    const float* v   = (const float*)d_in[4];  // [1][256]

    float* out   = (float*)d_out;
    float* ctx   = out;                 // [64][256]  output 0
    float* probs = out + Bq * Eq;       // [64][2048] output 1 (escore first)

    char* ws = (char*)d_ws;
    float*  ctxp   = (float*)ws;                        // 2 MB  [32][64][256]
    float*  denomp = (float*)(ws + (32*Bq*Eq)*4);       // 8 KB  [32][64]
    float*  dproj  = (float*)(ws + (32*Bq*Eq)*4 + 32*Bq*4);            // 64 KB
    ushort* w1sw   = (ushort*)(ws + (32*Bq*Eq)*4 + 32*Bq*4 + Bq*Iq*4); // 128 KB

    // all ws buffers are fully overwritten each call -> no memsets needed
    prep_kernel<<<dim3(96), dim3(256), 0, stream>>>(w1, w1sw, dec, w2, dproj);
    scores_ctx_kernel<<<dim3(Tq / 64, Bq), dim3(256), 0, stream>>>(
        enc, w1sw, v, dproj, probs, ctxp, denomp);
    finalize_kernel<<<dim3(Bq), dim3(256), 0, stream>>>(ctxp, denomp, probs, ctx);
}

// Round 7
// 233.925 us; speedup vs baseline: 1.1311x; 1.0024x over previous
//
#include <hip/hip_runtime.h>
#include <hip/hip_bf16.h>
#include <math.h>

#define Bq 64
#define Tq 2048
#define Eq 256
#define Dq 256
#define Iq 256

using short8  = __attribute__((ext_vector_type(8))) short;
using floatx4 = __attribute__((ext_vector_type(4))) float;

__device__ __forceinline__ float fast_tanh(float x) {
    float e = __expf(2.0f * x);
    return 1.0f - 2.0f / (e + 1.0f);
}

__device__ __forceinline__ ushort f2bf(float x) {
    union { __hip_bfloat16 h; ushort u; } c;
    c.h = __float2bfloat16(x);
    return c.u;
}

// Fused prep:
//  blocks 0..31 : w1 fp32 -> bf16 fragment-ordered: w1sw[kc][i][8], kc=k/8
//  blocks 32..95: dec_proj[b][i] = sum_d dec[b][d]*w2[i][d], b=blockIdx-32
__global__ __launch_bounds__(256) void prep_kernel(
    const float* __restrict__ w1, ushort* __restrict__ w1sw,
    const float* __restrict__ dec, const float* __restrict__ w2,
    float* __restrict__ dproj)
{
    if (blockIdx.x < 32) {
        const int kc = blockIdx.x;
        const int i  = threadIdx.x;
        const float* src = w1 + i * Eq + kc * 8;
        float4 f0 = *(const float4*)src;
        float4 f1 = *(const float4*)(src + 4);
        ushort u[8] = { f2bf(f0.x), f2bf(f0.y), f2bf(f0.z), f2bf(f0.w),
                        f2bf(f1.x), f2bf(f1.y), f2bf(f1.z), f2bf(f1.w) };
        *(short8*)&w1sw[(kc * 256 + i) * 8] = *(short8*)u;
    } else {
        const int b = blockIdx.x - 32;
        const int i = threadIdx.x;
        __shared__ float dls[Dq];
        dls[i] = dec[b * Dq + i];
        __syncthreads();
        const float* w2r = w2 + i * Dq;
        float acc = 0.f;
        #pragma unroll 8
        for (int d = 0; d < Dq; ++d) acc += dls[d] * w2r[d];
        dproj[b * Iq + i] = acc;
    }
}

// Fused scores + unnormalized-context. FULL-K staging:
// whole 64x256 A tile staged in one shot (each wave reads full 1-KB enc
// rows -> contiguous, sweeps all HBM channels), ONE barrier, then all 8
// MFMA k-steps (B direct from L2, 1-step prefetch). Epilogue fused.
__global__ __launch_bounds__(256, 3) void scores_ctx_kernel(
    const float*  __restrict__ enc,    // [B][T][E] fp32
    const ushort* __restrict__ w1sw,   // fragment-ordered bf16 [32 kc][256 i][8]
    const float*  __restrict__ v,      // [I]
    const float*  __restrict__ dproj,  // [B][I]
    float* __restrict__ escore,        // [B][T] unnormalized exp (probs buffer)
    float* __restrict__ ctxp,          // [32][B][E] context partials
    float* __restrict__ denomp)        // [32][B]
{
    const int b   = blockIdx.y;
    const int bx  = blockIdx.x;
    const int t0  = bx * 64;
    const int tid = threadIdx.x;
    const int w   = tid >> 6;
    const int l   = tid & 63;
    const int l15 = l & 15;
    const int lq  = l >> 4;
    const int iBase = w * 64 + l15;

    // A tile bf16, row pad 264 (stride 132 dw = 4 mod 32 -> 2-way-free b128)
    __shared__ ushort As[64 * 264];    // 33.8 KB; aliased by epilogue buffers
    __shared__ float vls[Iq], dls[Iq];
    __shared__ float pv[64];

    vls[tid] = v[tid];
    dls[tid] = dproj[b * Iq + tid];

    floatx4 acc[4][4];
    #pragma unroll
    for (int mi = 0; mi < 4; ++mi)
        #pragma unroll
        for (int ni = 0; ni < 4; ++ni)
            acc[mi][ni] = (floatx4)0.f;

    const float* encB = enc + ((size_t)b * Tq + t0) * Eq;
    const int lane4 = l * 4;     // this lane's float4 column within a row

    // stage: round j covers rows j*4 .. j*4+3; wave w takes row j*4+w and
    // reads it CONTIGUOUSLY (64 lanes x 16 B = the whole 1-KB row).
    float4 pre[8];
    #pragma unroll
    for (int j = 0; j < 8; ++j)
        pre[j] = *(const float4*)&encB[(j * 4 + w) * Eq + lane4];
    #pragma unroll
    for (int j = 0; j < 8; ++j) {
        ushort4 u;
        u.x = f2bf(pre[j].x); u.y = f2bf(pre[j].y);
        u.z = f2bf(pre[j].z); u.w = f2bf(pre[j].w);
        *(ushort4*)&As[(j * 4 + w) * 264 + lane4] = u;
    }
    #pragma unroll
    for (int j = 8; j < 16; ++j)
        pre[j - 8] = *(const float4*)&encB[(j * 4 + w) * Eq + lane4];
    #pragma unroll
    for (int j = 8; j < 16; ++j) {
        ushort4 u;
        u.x = f2bf(pre[j - 8].x); u.y = f2bf(pre[j - 8].y);
        u.z = f2bf(pre[j - 8].z); u.w = f2bf(pre[j - 8].w);
        *(ushort4*)&As[(j * 4 + w) * 264 + lane4] = u;
    }
    __syncthreads();

    // compute: 8 k-steps x (4m x 4n) MFMAs; B from L2 with 1-step prefetch
    short8 bcur[4], bnext[4];
    #pragma unroll
    for (int ni = 0; ni < 4; ++ni)
        bcur[ni] = *(const short8*)&w1sw[((size_t)lq * 256 + iBase + ni * 16) * 8];
    #pragma unroll
    for (int kstep = 0; kstep < 8; ++kstep) {
        if (kstep < 7) {
            const int kc = (kstep + 1) * 4 + lq;
            #pragma unroll
            for (int ni = 0; ni < 4; ++ni)
                bnext[ni] = *(const short8*)&w1sw[((size_t)kc * 256 + iBase + ni * 16) * 8];
        }
        short8 af[4];
        #pragma unroll
        for (int mi = 0; mi < 4; ++mi)
            af[mi] = *(const short8*)&As[(mi * 16 + l15) * 264 + kstep * 32 + lq * 8];
        #pragma unroll
        for (int mi = 0; mi < 4; ++mi)
            #pragma unroll
            for (int ni = 0; ni < 4; ++ni)
                acc[mi][ni] = __builtin_amdgcn_mfma_f32_16x16x32_bf16(
                    af[mi], bcur[ni], acc[mi][ni], 0, 0, 0);
        #pragma unroll
        for (int ni = 0; ni < 4; ++ni) bcur[ni] = bnext[ni];
    }

    // epilogue: tanh + v-weight. C layout: col(i)=l15, row(t)=lq*4+reg.
    float part[4][4];
    #pragma unroll
    for (int mi = 0; mi < 4; ++mi)
        #pragma unroll
        for (int r = 0; r < 4; ++r) part[mi][r] = 0.f;

    #pragma unroll
    for (int ni = 0; ni < 4; ++ni) {
        const int i   = w * 64 + ni * 16 + l15;
        const float vi = vls[i];
        const float dp = dls[i];
        #pragma unroll
        for (int mi = 0; mi < 4; ++mi)
            #pragma unroll
            for (int r = 0; r < 4; ++r)
                part[mi][r] += vi * fast_tanh(acc[mi][ni][r] + dp);
    }

    __syncthreads();   // all waves done reading As before overwrite

    // LDS transpose-reduce in As-aliased buffer: [(t_global)*20 + l15]
    float* red2 = (float*)As;          // 20.5 KB <= 33.8 KB
    #pragma unroll
    for (int mi = 0; mi < 4; ++mi)
        #pragma unroll
        for (int r = 0; r < 4; ++r)
            red2[(w * 64 + mi * 16 + lq * 4 + r) * 20 + l15] = part[mi][r];
    __syncthreads();

    if (tid < 64) {
        float s = 0.f;
        #pragma unroll
        for (int ww = 0; ww < 4; ++ww) {
            const float* rp = red2 + (ww * 64 + tid) * 20;
            float4 q0 = *(const float4*)(rp + 0);
            float4 q1 = *(const float4*)(rp + 4);
            float4 q2 = *(const float4*)(rp + 8);
            float4 q3 = *(const float4*)(rp + 12);
            s += (q0.x + q0.y + q0.z + q0.w) + (q1.x + q1.y + q1.z + q1.w)
               + (q2.x + q2.y + q2.z + q2.w) + (q3.x + q3.y + q3.z + q3.w);
        }
        const float es = __expf(s);   // |s| <= 16 -> safe in fp32 w/o max-sub
        pv[tid] = es;
        escore[(size_t)b * Tq + t0 + tid] = es;
        float tot = es;
        tot += __shfl_xor(tot, 1);  tot += __shfl_xor(tot, 2);
        tot += __shfl_xor(tot, 4);  tot += __shfl_xor(tot, 8);
        tot += __shfl_xor(tot, 16); tot += __shfl_xor(tot, 32);
        if (tid == 0) denomp[bx * Bq + b] = tot;
    }
    __syncthreads();

    // fused context partial: ctxp[bx][b][e] = sum_t pv[t]*enc[t][e]
    // (row-contiguous reads; tile is L2-hot from staging)
    const int tg = tid >> 6;            // = w
    const int el = (tid & 63) * 4;      // e in float4 units
    float4 a = {0.f, 0.f, 0.f, 0.f};
    #pragma unroll 4
    for (int tt = 0; tt < 16; ++tt) {
        const int t = tg * 16 + tt;     // wave-uniform
        const float pt = pv[t];
        float4 ev = *(const float4*)&encB[t * Eq + el];
        a.x += pt * ev.x; a.y += pt * ev.y; a.z += pt * ev.z; a.w += pt * ev.w;
    }
    float* redf = (float*)As;           // reuse (barrier above passed)
    *(float4*)&redf[tg * 256 + el] = a;
    __syncthreads();
    if (tg == 0) {
        float4 a0 = *(const float4*)&redf[0 * 256 + el];
        float4 a1 = *(const float4*)&redf[1 * 256 + el];
        float4 a2 = *(const float4*)&redf[2 * 256 + el];
        float4 a3 = *(const float4*)&redf[3 * 256 + el];
        float4 o;
        o.x = a0.x + a1.x + a2.x + a3.x;
        o.y = a0.y + a1.y + a2.y + a3.y;
        o.z = a0.z + a1.z + a2.z + a3.z;
        o.w = a0.w + a1.w + a2.w + a3.w;
        *(float4*)&ctxp[((size_t)bx * Bq + b) * Eq + el] = o;
    }
}

// One block per b: denom = sum_c denomp[c][b]; probs *= 1/denom (in place);
// ctx[b][e] = (sum_c ctxp[c][b][e]) / denom.
__global__ __launch_bounds__(256) void finalize_kernel(
    const float* __restrict__ ctxp, const float* __restrict__ denomp,
    float* __restrict__ probs, float* __restrict__ ctx)
{
    const int b   = blockIdx.x;
    const int tid = threadIdx.x;

    float d = denomp[(tid & 31) * Bq + b];
    d += __shfl_xor(d, 1);  d += __shfl_xor(d, 2);  d += __shfl_xor(d, 4);
    d += __shfl_xor(d, 8);  d += __shfl_xor(d, 16);
    const float inv = 1.0f / d;

    float* prow = probs + (size_t)b * Tq + tid * 8;
    float4 p0 = *(const float4*)(prow + 0);
    float4 p1 = *(const float4*)(prow + 4);
    p0.x *= inv; p0.y *= inv; p0.z *= inv; p0.w *= inv;
    p1.x *= inv; p1.y *= inv; p1.z *= inv; p1.w *= inv;
    *(float4*)(prow + 0) = p0;
    *(float4*)(prow + 4) = p1;

    float s = 0.f;
    #pragma unroll 8
    for (int c = 0; c < 32; ++c)
        s += ctxp[((size_t)c * Bq + b) * Eq + tid];
    ctx[b * Eq + tid] = s * inv;
}

extern "C" void kernel_launch(void* const* d_in, const int* in_sizes, int n_in,
                              void* d_out, int out_size, void* d_ws, size_t ws_size,
                              hipStream_t stream) {
    const float* enc = (const float*)d_in[0];  // [64][2048][256]
    const float* dec = (const float*)d_in[1];  // [64][256]
    const float* w1  = (const float*)d_in[2];  // [256][256]
    const float* w2  = (const float*)d_in[3];  // [256][256]
    const float* v   = (const float*)d_in[4];  // [1][256]

    float* out   = (float*)d_out;
    float* ctx   = out;                 // [64][256]  output 0
    float* probs = out + Bq * Eq;       // [64][2048] output 1 (escore first)

    char* ws = (char*)d_ws;
    float*  ctxp   = (float*)ws;                        // 2 MB  [32][64][256]
    float*  denomp = (float*)(ws + (32*Bq*Eq)*4);       // 8 KB  [32][64]
    float*  dproj  = (float*)(ws + (32*Bq*Eq)*4 + 32*Bq*4);            // 64 KB
    ushort* w1sw   = (ushort*)(ws + (32*Bq*Eq)*4 + 32*Bq*4 + Bq*Iq*4); // 128 KB

    // all ws buffers are fully overwritten each call -> no memsets needed
    prep_kernel<<<dim3(96), dim3(256), 0, stream>>>(w1, w1sw, dec, w2, dproj);
    scores_ctx_kernel<<<dim3(Tq / 64, Bq), dim3(256), 0, stream>>>(
        enc, w1sw, v, dproj, probs, ctxp, denomp);
    finalize_kernel<<<dim3(Bq), dim3(256), 0, stream>>>(ctxp, denomp, probs, ctx);
}